// Round 1
// baseline (100.867 us; speedup 1.0000x reference)
//
#include <hip/hip_runtime.h>

#define NNODES   131072
#define NPER     2048
#define NGRAPH   64
#define KKEEP    1024
#define NCH      256
#define NEDGE    4194304

// float-element offsets into d_out (return order: x_out, new_ei, batch_out, perm, score_perm)
#define OFF_EI    16777216   // 65536*256
#define OFF_BATCH 25165824   // OFF_EI + 2*NEDGE
#define OFF_PERM  25231360
#define OFF_SCP   25296896

// Bitwise replica of XLA-CPU's f32 fast tanh (Eigen-derived rational approx):
// clamp to +-7.90531110763549805, Horner with separate mul/add (no FMA),
// IEEE f32 divide, passthrough for |x| < 0.0004.
__device__ __forceinline__ float xla_tanhf(float x) {
  const float kClamp = 7.90531110763549805f;
  float xc = fminf(fmaxf(x, -kClamp), kClamp);
  float x2 = __fmul_rn(xc, xc);
  float p;
  p = __fadd_rn(__fmul_rn(x2, -2.76076847742355e-16f), 2.00018790482477e-13f);
  p = __fadd_rn(__fmul_rn(x2, p), -8.60467152213735e-11f);
  p = __fadd_rn(__fmul_rn(x2, p), 5.12229709037114e-08f);
  p = __fadd_rn(__fmul_rn(x2, p), 1.48572235717979e-05f);
  p = __fadd_rn(__fmul_rn(x2, p), 6.37261928875436e-04f);
  p = __fadd_rn(__fmul_rn(x2, p), 4.89352455891786e-03f);
  float num = __fmul_rn(xc, p);
  float q;
  q = __fadd_rn(__fmul_rn(x2, 1.19825839466702e-06f), 1.18534705686654e-04f);
  q = __fadd_rn(__fmul_rn(x2, q), 2.26843463243900e-03f);
  q = __fadd_rn(__fmul_rn(x2, q), 4.89352518554385e-03f);
  float r = __fdiv_rn(num, q);
  return (fabsf(x) < 0.0004f) ? x : r;
}

// One block = 32 nodes. Stage 32x256 f32 rows in LDS (stride 264 -> 2-way bank, free),
// 8 threads per node each own one of XLA-gemv's 8 sequential mul/add accumulator
// chains (cols 8i+j), then high/low-half pairwise shuffle tree => bitwise replica
// of the reference dot reduction shape. Also fuses node_idx = -1 init.
__global__ __launch_bounds__(256) void k_score(const float* __restrict__ x,
                                               const float* __restrict__ qv,
                                               float* __restrict__ score,
                                               int* __restrict__ node_idx) {
  __shared__ float xs[32 * 264];
  __shared__ float qs[256];
  const int t = threadIdx.x;
  const int bid = blockIdx.x;          // 4096 blocks x 32 rows = 131072 rows
  qs[t] = qv[t];
  const int gid = bid * 256 + t;
  if (gid < NNODES) node_idx[gid] = -1;
  const float* xblk = x + (size_t)bid * 32 * 256;
#pragma unroll
  for (int it = 0; it < 8; ++it) {
    int flat = it * 1024 + t * 4;
    int row = flat >> 8, col = flat & 255;
    float4 v = *reinterpret_cast<const float4*>(xblk + flat);
    *reinterpret_cast<float4*>(&xs[row * 264 + col]) = v;
  }
  __syncthreads();
  const int node = t >> 3;
  const int j = t & 7;
  const float* xr = &xs[node * 264];
  float a = 0.0f;
#pragma unroll
  for (int i = 0; i < 32; ++i) {
    int c = 8 * i + j;
    a = __fadd_rn(__fmul_rn(xr[c], qs[c]), a);   // sequential chain, no FMA
  }
  // pairwise half-split tree: (j)+(j+4), then +2, then +1
  float s = __fadd_rn(a, __shfl_xor(a, 4, 64));
  s = __fadd_rn(s, __shfl_xor(s, 2, 64));
  s = __fadd_rn(s, __shfl_xor(s, 1, 64));
  if (j == 0) score[bid * 32 + node] = xla_tanhf(s);
}

// One block per graph: bitonic sort of 2048 packed keys in LDS.
// key = (~orderable(score) << 32) | local_index ; ascending sort == descending
// score with index-ascending ties (lax.top_k stable semantics).
__global__ __launch_bounds__(1024) void k_topk(const float* __restrict__ score,
                                               int* __restrict__ node_idx,
                                               int* __restrict__ ws_perm,
                                               float* __restrict__ out) {
  __shared__ unsigned long long keys[NPER];
  const int b = blockIdx.x;
  const int t = threadIdx.x;
#pragma unroll
  for (int e = t; e < NPER; e += 1024) {
    float s = score[b * NPER + e];
    unsigned u = __float_as_uint(s);
    unsigned ks = (u & 0x80000000u) ? ~u : (u | 0x80000000u);  // ascending-order map
    keys[e] = ((unsigned long long)(~ks) << 32) | (unsigned long long)(unsigned)e;
  }
  __syncthreads();
  for (int k = 2; k <= NPER; k <<= 1) {
    for (int j = k >> 1; j > 0; j >>= 1) {
      int i = ((t & ~(j - 1)) << 1) | (t & (j - 1));
      int pr = i | j;
      bool up = ((i & k) == 0);
      unsigned long long a = keys[i], c = keys[pr];
      if ((c < a) == up) { keys[i] = c; keys[pr] = a; }
      __syncthreads();
    }
  }
  if (t < KKEEP) {
    unsigned long long key = keys[t];
    int loc = (int)(unsigned)(key & 0xFFFFFFFFull);
    int g = b * NPER + loc;
    int o = b * KKEEP + t;
    float sc = score[g];
    out[OFF_PERM + o]  = (float)g;
    out[OFF_BATCH + o] = (float)b;
    out[OFF_SCP + o]   = sc;
    ws_perm[o] = g;
    node_idx[g] = o;
  }
}

// One wave per kept row: x_out[r] = x[perm[r]] * score[perm[r]]
__global__ __launch_bounds__(256) void k_gather(const float* __restrict__ x,
                                                const int* __restrict__ ws_perm,
                                                const float* __restrict__ score,
                                                float* __restrict__ out) {
  const int r = blockIdx.x * 4 + (threadIdx.x >> 6);
  const int lane = threadIdx.x & 63;
  const int p = ws_perm[r];
  const float s = score[p];
  float4 v = reinterpret_cast<const float4*>(x)[(size_t)p * 64 + lane];
  float4 o;
  o.x = __fmul_rn(v.x, s); o.y = __fmul_rn(v.y, s);
  o.z = __fmul_rn(v.z, s); o.w = __fmul_rn(v.w, s);
  reinterpret_cast<float4*>(out)[(size_t)r * 64 + lane] = o;
}

// 4 edges per thread: relabel via node_idx (512 KB table, L2-resident),
// -1/-1 if either endpoint dropped. Outputs written as float values.
__global__ __launch_bounds__(256) void k_edges(const int* __restrict__ ei,
                                               const int* __restrict__ node_idx,
                                               float* __restrict__ out) {
  const int tid = blockIdx.x * 256 + threadIdx.x;   // NEDGE/4 threads
  int4 s4 = reinterpret_cast<const int4*>(ei)[tid];
  int4 d4 = reinterpret_cast<const int4*>(ei + NEDGE)[tid];
  float4 o0, o1;
  { int na = node_idx[s4.x], nb = node_idx[d4.x]; bool v = (na >= 0) && (nb >= 0);
    o0.x = v ? (float)na : -1.0f; o1.x = v ? (float)nb : -1.0f; }
  { int na = node_idx[s4.y], nb = node_idx[d4.y]; bool v = (na >= 0) && (nb >= 0);
    o0.y = v ? (float)na : -1.0f; o1.y = v ? (float)nb : -1.0f; }
  { int na = node_idx[s4.z], nb = node_idx[d4.z]; bool v = (na >= 0) && (nb >= 0);
    o0.z = v ? (float)na : -1.0f; o1.z = v ? (float)nb : -1.0f; }
  { int na = node_idx[s4.w], nb = node_idx[d4.w]; bool v = (na >= 0) && (nb >= 0);
    o0.w = v ? (float)na : -1.0f; o1.w = v ? (float)nb : -1.0f; }
  float* oei = out + OFF_EI;
  reinterpret_cast<float4*>(oei)[tid] = o0;
  reinterpret_cast<float4*>(oei + NEDGE)[tid] = o1;
}

extern "C" void kernel_launch(void* const* d_in, const int* in_sizes, int n_in,
                              void* d_out, int out_size, void* d_ws, size_t ws_size,
                              hipStream_t stream) {
  const float* x  = (const float*)d_in[0];   // [131072, 256] f32
  const int*   ei = (const int*)d_in[1];     // [2, 4194304] i32
  const float* qv = (const float*)d_in[2];   // [256] f32
  // d_in[3] (batch) not needed: batch[perm] == graph id by construction.
  float* out = (float*)d_out;

  float* score    = (float*)d_ws;               // 131072 f32
  int*   node_idx = (int*)d_ws + NNODES;        // 131072 i32
  int*   ws_perm  = (int*)d_ws + 2 * NNODES;    // 65536 i32

  k_score<<<4096, 256, 0, stream>>>(x, qv, score, node_idx);
  k_topk<<<NGRAPH, 1024, 0, stream>>>(score, node_idx, ws_perm, out);
  k_gather<<<16384, 256, 0, stream>>>(x, ws_perm, score, out);
  k_edges<<<NEDGE / 4 / 256, 256, 0, stream>>>(ei, node_idx, out);
}

// Round 2
// 100.457 us; speedup vs baseline: 1.0041x; 1.0041x over previous
//
#include <hip/hip_runtime.h>

#define NNODES   131072
#define NPER     2048
#define NGRAPH   64
#define KKEEP    1024
#define NCH      256
#define NEDGE    4194304

// float-element offsets into d_out (return order: x_out, new_ei, batch_out, perm, score_perm)
#define OFF_EI    16777216   // 65536*256
#define OFF_BATCH 25165824   // OFF_EI + 2*NEDGE
#define OFF_PERM  25231360
#define OFF_SCP   25296896

// Bitwise replica of XLA-CPU's f32 fast tanh (Eigen-derived rational approx):
// clamp to +-7.90531110763549805, Horner with separate mul/add (no FMA),
// IEEE f32 divide, passthrough for |x| < 0.0004.
__device__ __forceinline__ float xla_tanhf(float x) {
  const float kClamp = 7.90531110763549805f;
  float xc = fminf(fmaxf(x, -kClamp), kClamp);
  float x2 = __fmul_rn(xc, xc);
  float p;
  p = __fadd_rn(__fmul_rn(x2, -2.76076847742355e-16f), 2.00018790482477e-13f);
  p = __fadd_rn(__fmul_rn(x2, p), -8.60467152213735e-11f);
  p = __fadd_rn(__fmul_rn(x2, p), 5.12229709037114e-08f);
  p = __fadd_rn(__fmul_rn(x2, p), 1.48572235717979e-05f);
  p = __fadd_rn(__fmul_rn(x2, p), 6.37261928875436e-04f);
  p = __fadd_rn(__fmul_rn(x2, p), 4.89352455891786e-03f);
  float num = __fmul_rn(xc, p);
  float q;
  q = __fadd_rn(__fmul_rn(x2, 1.19825839466702e-06f), 1.18534705686654e-04f);
  q = __fadd_rn(__fmul_rn(x2, q), 2.26843463243900e-03f);
  q = __fadd_rn(__fmul_rn(x2, q), 4.89352518554385e-03f);
  float r = __fdiv_rn(num, q);
  return (fabsf(x) < 0.0004f) ? x : r;
}

// One block = 32 nodes. Stage 32x256 f32 rows in LDS (stride 264 -> 2-way bank, free),
// 8 threads per node each own one of XLA-gemv's 8 sequential mul/add accumulator
// chains (cols 8i+j), then high/low-half pairwise shuffle tree => bitwise replica
// of the reference dot reduction shape. Also fuses node_idx = -1 init.
__global__ __launch_bounds__(256) void k_score(const float* __restrict__ x,
                                               const float* __restrict__ qv,
                                               float* __restrict__ score,
                                               int* __restrict__ node_idx) {
  __shared__ float xs[32 * 264];
  __shared__ float qs[256];
  const int t = threadIdx.x;
  const int bid = blockIdx.x;          // 4096 blocks x 32 rows = 131072 rows
  qs[t] = qv[t];
  const int gid = bid * 256 + t;
  if (gid < NNODES) node_idx[gid] = -1;
  const float* xblk = x + (size_t)bid * 32 * 256;
#pragma unroll
  for (int it = 0; it < 8; ++it) {
    int flat = it * 1024 + t * 4;
    int row = flat >> 8, col = flat & 255;
    float4 v = *reinterpret_cast<const float4*>(xblk + flat);
    *reinterpret_cast<float4*>(&xs[row * 264 + col]) = v;
  }
  __syncthreads();
  const int node = t >> 3;
  const int j = t & 7;
  const float* xr = &xs[node * 264];
  float a = 0.0f;
#pragma unroll
  for (int i = 0; i < 32; ++i) {
    int c = 8 * i + j;
    a = __fadd_rn(__fmul_rn(xr[c], qs[c]), a);   // sequential chain, no FMA
  }
  // pairwise half-split tree: (j)+(j+4), then +2, then +1
  float s = __fadd_rn(a, __shfl_xor(a, 4, 64));
  s = __fadd_rn(s, __shfl_xor(s, 2, 64));
  s = __fadd_rn(s, __shfl_xor(s, 1, 64));
  if (j == 0) score[bid * 32 + node] = xla_tanhf(s);
}

// One block per graph: bitonic sort of 2048 packed keys in LDS.
// key = (~orderable(score) << 32) | local_index ; ascending sort == descending
// score with index-ascending ties (lax.top_k stable semantics).
__global__ __launch_bounds__(1024) void k_topk(const float* __restrict__ score,
                                               int* __restrict__ node_idx,
                                               int* __restrict__ ws_perm,
                                               float* __restrict__ out) {
  __shared__ unsigned long long keys[NPER];
  const int b = blockIdx.x;
  const int t = threadIdx.x;
#pragma unroll
  for (int e = t; e < NPER; e += 1024) {
    float s = score[b * NPER + e];
    unsigned u = __float_as_uint(s);
    unsigned ks = (u & 0x80000000u) ? ~u : (u | 0x80000000u);  // ascending-order map
    keys[e] = ((unsigned long long)(~ks) << 32) | (unsigned long long)(unsigned)e;
  }
  __syncthreads();
  for (int k = 2; k <= NPER; k <<= 1) {
    for (int j = k >> 1; j > 0; j >>= 1) {
      int i = ((t & ~(j - 1)) << 1) | (t & (j - 1));
      int pr = i | j;
      bool up = ((i & k) == 0);
      unsigned long long a = keys[i], c = keys[pr];
      if ((c < a) == up) { keys[i] = c; keys[pr] = a; }
      __syncthreads();
    }
  }
  if (t < KKEEP) {
    unsigned long long key = keys[t];
    int loc = (int)(unsigned)(key & 0xFFFFFFFFull);
    int g = b * NPER + loc;
    int o = b * KKEEP + t;
    float sc = score[g];
    out[OFF_PERM + o]  = (float)g;
    out[OFF_BATCH + o] = (float)b;
    out[OFF_SCP + o]   = sc;
    ws_perm[o] = g;
    node_idx[g] = o;
  }
}

// One wave per kept row: x_out[r] = x[perm[r]] * score[perm[r]]
__global__ __launch_bounds__(256) void k_gather(const float* __restrict__ x,
                                                const int* __restrict__ ws_perm,
                                                const float* __restrict__ score,
                                                float* __restrict__ out) {
  const int r = blockIdx.x * 4 + (threadIdx.x >> 6);
  const int lane = threadIdx.x & 63;
  const int p = ws_perm[r];
  const float s = score[p];
  float4 v = reinterpret_cast<const float4*>(x)[(size_t)p * 64 + lane];
  float4 o;
  o.x = __fmul_rn(v.x, s); o.y = __fmul_rn(v.y, s);
  o.z = __fmul_rn(v.z, s); o.w = __fmul_rn(v.w, s);
  reinterpret_cast<float4*>(out)[(size_t)r * 64 + lane] = o;
}

// 4 edges per thread: relabel via node_idx (512 KB table, L2-resident),
// -1/-1 if either endpoint dropped. Outputs written as float values.
__global__ __launch_bounds__(256) void k_edges(const int* __restrict__ ei,
                                               const int* __restrict__ node_idx,
                                               float* __restrict__ out) {
  const int tid = blockIdx.x * 256 + threadIdx.x;   // NEDGE/4 threads
  int4 s4 = reinterpret_cast<const int4*>(ei)[tid];
  int4 d4 = reinterpret_cast<const int4*>(ei + NEDGE)[tid];
  float4 o0, o1;
  { int na = node_idx[s4.x], nb = node_idx[d4.x]; bool v = (na >= 0) && (nb >= 0);
    o0.x = v ? (float)na : -1.0f; o1.x = v ? (float)nb : -1.0f; }
  { int na = node_idx[s4.y], nb = node_idx[d4.y]; bool v = (na >= 0) && (nb >= 0);
    o0.y = v ? (float)na : -1.0f; o1.y = v ? (float)nb : -1.0f; }
  { int na = node_idx[s4.z], nb = node_idx[d4.z]; bool v = (na >= 0) && (nb >= 0);
    o0.z = v ? (float)na : -1.0f; o1.z = v ? (float)nb : -1.0f; }
  { int na = node_idx[s4.w], nb = node_idx[d4.w]; bool v = (na >= 0) && (nb >= 0);
    o0.w = v ? (float)na : -1.0f; o1.w = v ? (float)nb : -1.0f; }
  float* oei = out + OFF_EI;
  reinterpret_cast<float4*>(oei)[tid] = o0;
  reinterpret_cast<float4*>(oei + NEDGE)[tid] = o1;
}

extern "C" void kernel_launch(void* const* d_in, const int* in_sizes, int n_in,
                              void* d_out, int out_size, void* d_ws, size_t ws_size,
                              hipStream_t stream) {
  const float* x  = (const float*)d_in[0];   // [131072, 256] f32
  const int*   ei = (const int*)d_in[1];     // [2, 4194304] i32
  const float* qv = (const float*)d_in[2];   // [256] f32
  // d_in[3] (batch) not needed: batch[perm] == graph id by construction.
  float* out = (float*)d_out;

  float* score    = (float*)d_ws;               // 131072 f32
  int*   node_idx = (int*)d_ws + NNODES;        // 131072 i32
  int*   ws_perm  = (int*)d_ws + 2 * NNODES;    // 65536 i32

  k_score<<<4096, 256, 0, stream>>>(x, qv, score, node_idx);
  k_topk<<<NGRAPH, 1024, 0, stream>>>(score, node_idx, ws_perm, out);
  k_gather<<<16384, 256, 0, stream>>>(x, ws_perm, score, out);
  k_edges<<<NEDGE / 4 / 256, 256, 0, stream>>>(ei, node_idx, out);
}